// Round 1
// baseline (170.628 us; speedup 1.0000x reference)
//
#include <hip/hip_runtime.h>
#include <hip/hip_bf16.h>

// Problem constants
#define B_      4
#define C_IN    64
#define H_      64
#define W_      64
#define OUT_CH  128
#define HP_     66          // padded height (halo = features(0))
#define WPAD_   66          // padded width
#define CF      576         // K per tap: 9 features * 64 channels, cf = j*64 + c
#define WP_ELEMS (9 * OUT_CH * CF)
#define WP_BYTES (WP_ELEMS * 2)

typedef __bf16 bf16x8 __attribute__((ext_vector_type(8)));
typedef float  f32x4  __attribute__((ext_vector_type(4)));

// silu + cubic B-spline bases (Cox-de Boor, uniform grid h=0.4 over [-1,1],
// extended by 3 on each side). Bitwise-identical grid/indicator semantics to ref.
__device__ __forceinline__ void compute_features(float x, float f[9]) {
    f[0] = x / (1.0f + __expf(-x));            // silu
    float g[12];
#pragma unroll
    for (int i = 0; i < 12; ++i) g[i] = (float)(i - 3) * 0.4f - 1.0f;
    float bb[11];
#pragma unroll
    for (int i = 0; i < 11; ++i) bb[i] = (x >= g[i] && x < g[i + 1]) ? 1.0f : 0.0f;
#pragma unroll
    for (int i = 0; i < 10; ++i)
        bb[i] = (x - g[i]) * (1.0f / (g[i + 1] - g[i])) * bb[i]
              + (g[i + 2] - x) * (1.0f / (g[i + 2] - g[i + 1])) * bb[i + 1];
#pragma unroll
    for (int i = 0; i < 9; ++i)
        bb[i] = (x - g[i]) * (1.0f / (g[i + 2] - g[i])) * bb[i]
              + (g[i + 3] - x) * (1.0f / (g[i + 3] - g[i + 1])) * bb[i + 1];
#pragma unroll
    for (int i = 0; i < 8; ++i)
        bb[i] = (x - g[i]) * (1.0f / (g[i + 3] - g[i])) * bb[i]
              + (g[i + 4] - x) * (1.0f / (g[i + 4] - g[i + 1])) * bb[i + 1];
#pragma unroll
    for (int i = 0; i < 8; ++i) f[1 + i] = bb[i];
}

// Kernel 1: pack merged weights -> bf16, Wp[(tap*128 + o)*576 + j*64 + c]
// j==0: base_weight[o][d];  j>=1: spline_weight[o][d][j-1] * spline_scaler[o][d]
// with d = c*9 + tap  (patch feature order (C, kh, kw), tap = kh*3+kw)
__global__ __launch_bounds__(256) void pack_kernel(
        const float* __restrict__ bw, const float* __restrict__ sw,
        const float* __restrict__ sc, __hip_bfloat16* __restrict__ Wp) {
    int idx = blockIdx.x * 256 + threadIdx.x;
    if (idx >= WP_ELEMS) return;
    int jc   = idx % CF;
    int rest = idx / CF;        // tap*128 + o
    int o    = rest % OUT_CH;
    int tap  = rest / OUT_CH;
    int j = jc >> 6;
    int c = jc & 63;
    int d = c * 9 + tap;
    float v;
    if (j == 0) v = bw[o * 576 + d];
    else        v = sw[(o * 576 + d) * 8 + (j - 1)] * sc[o * 576 + d];
    Wp[idx] = __float2bfloat16(v);
}

// Kernel 2: per-pixel features with halo. F[((b*66+hp)*66+wp)*576 + j*64 + c]
// Halo (hp/wp on border) gets features(0) — matches zero-padded im2col.
__global__ __launch_bounds__(256) void feat_kernel(
        const float* __restrict__ x, __hip_bfloat16* __restrict__ F) {
    int b  = blockIdx.x / HP_;
    int hp = blockIdx.x % HP_;
    int c    = threadIdx.x & 63;
    int wsub = threadIdx.x >> 6;      // 0..3
    int h = hp - 1;
    for (int wp = wsub; wp < WPAD_; wp += 4) {
        int w = wp - 1;
        bool interior = (h >= 0) && (h < H_) && (w >= 0) && (w < W_);
        float xv = interior ? x[((b * C_IN + c) * H_ + h) * W_ + w] : 0.0f;
        float f[9];
        compute_features(xv, f);
        __hip_bfloat16* dst = F + (size_t)((b * HP_ + hp) * WPAD_ + wp) * CF + c;
#pragma unroll
        for (int j = 0; j < 9; ++j) dst[j * 64] = __float2bfloat16(f[j]);
    }
}

// Kernel 3: implicit-GEMM conv. Block tile: 128 out_ch (MFMA-M) x 128 pixels
// (MFMA-N). 4 waves in 2x2, each wave 64x64 = 4x4 tiles of 16x16x32 bf16.
// K loop: 9 taps x 9 chunks of 64 (2 MFMA k-steps each).
__global__ __launch_bounds__(256) void gemm_kernel(
        const __hip_bfloat16* __restrict__ Fb, const __hip_bfloat16* __restrict__ Wpb,
        float* __restrict__ out) {
    __shared__ ushort As[128][72];   // features: [pixel][k], +8 pad (144B stride)
    __shared__ ushort Bs[128][72];   // weights:  [o][k]

    const ushort* F  = (const ushort*)Fb;
    const ushort* Wp = (const ushort*)Wpb;

    int tid  = threadIdx.x;
    int lane = tid & 63;
    int wave = tid >> 6;
    int wm = wave & 1;               // out_ch half
    int wn = wave >> 1;              // pixel half
    int l15 = lane & 15;
    int lq  = lane >> 4;             // 0..3

    int blk = blockIdx.x;            // 128 blocks: one per 128-pixel tile
    int b   = blk >> 5;
    int ho0 = (blk & 31) << 1;       // 2 image rows per tile

    f32x4 acc[4][4];
#pragma unroll
    for (int i = 0; i < 4; ++i)
#pragma unroll
        for (int j = 0; j < 4; ++j) acc[i][j] = (f32x4){0.f, 0.f, 0.f, 0.f};

    int c8 = tid & 7;                // 16B chunk id within a 64-elem row segment
    int r0 = tid >> 3;               // base row for staging

    for (int tap = 0; tap < 9; ++tap) {
        int kh = tap / 3;
        int kw = tap - kh * 3;
        for (int kc = 0; kc < 9; ++kc) {
            // ---- stage A (features, 128 pixels x 64 k) and B (weights) ----
#pragma unroll
            for (int i = 0; i < 4; ++i) {
                int row = i * 32 + r0;
                // features: pixel 'row' of this tile, shifted by tap
                int hp   = ho0 + (row >> 6) + kh;
                int wpix = (row & 63) + kw;
                const ushort* srcA = F + (size_t)((b * HP_ + hp) * WPAD_ + wpix) * CF
                                       + kc * 64 + c8 * 8;
                *(uint4*)&As[row][c8 * 8] = *(const uint4*)srcA;
                const ushort* srcB = Wp + (size_t)(tap * OUT_CH + row) * CF
                                        + kc * 64 + c8 * 8;
                *(uint4*)&Bs[row][c8 * 8] = *(const uint4*)srcB;
            }
            __syncthreads();
            // ---- 2 k-steps of MFMA ----
#pragma unroll
            for (int ks = 0; ks < 2; ++ks) {
                bf16x8 af[4], bf[4];
#pragma unroll
                for (int mt = 0; mt < 4; ++mt)
                    af[mt] = *(const bf16x8*)&Bs[wm * 64 + mt * 16 + l15][ks * 32 + lq * 8];
#pragma unroll
                for (int nt = 0; nt < 4; ++nt)
                    bf[nt] = *(const bf16x8*)&As[wn * 64 + nt * 16 + l15][ks * 32 + lq * 8];
#pragma unroll
                for (int mt = 0; mt < 4; ++mt)
#pragma unroll
                    for (int nt = 0; nt < 4; ++nt)
                        acc[mt][nt] = __builtin_amdgcn_mfma_f32_16x16x32_bf16(
                            af[mt], bf[nt], acc[mt][nt], 0, 0, 0);
            }
            __syncthreads();
        }
    }

    // ---- epilogue: D[row=o][col=pixel]; lane: o = q*4+r, pix = l15 ----
#pragma unroll
    for (int mt = 0; mt < 4; ++mt) {
        int o = wm * 64 + mt * 16 + lq * 4;
#pragma unroll
        for (int nt = 0; nt < 4; ++nt) {
            int pix = wn * 64 + nt * 16 + l15;
            int ho = ho0 + (pix >> 6);
            int wo = pix & 63;
            float* dst = out + ((size_t)(b * OUT_CH + o) << 12) + (ho << 6) + wo;
#pragma unroll
            for (int r = 0; r < 4; ++r)
                dst[(size_t)r << 12] = acc[mt][nt][r];
        }
    }
}

extern "C" void kernel_launch(void* const* d_in, const int* in_sizes, int n_in,
                              void* d_out, int out_size, void* d_ws, size_t ws_size,
                              hipStream_t stream) {
    const float* x  = (const float*)d_in[0];   // (4,64,64,64)
    const float* bw = (const float*)d_in[1];   // (128,576)
    const float* sw = (const float*)d_in[2];   // (128,576,8)
    const float* sc = (const float*)d_in[3];   // (128,576)
    float* out = (float*)d_out;                // (4,128,64,64) fp32

    // workspace: Wp (1.33 MB) then F (20.07 MB); both fully overwritten each call
    __hip_bfloat16* Wp = (__hip_bfloat16*)d_ws;
    __hip_bfloat16* F  = (__hip_bfloat16*)((char*)d_ws + WP_BYTES);

    pack_kernel<<<WP_ELEMS / 256, 256, 0, stream>>>(bw, sw, sc, Wp);
    feat_kernel<<<B_ * HP_, 256, 0, stream>>>(x, F);
    gemm_kernel<<<128, 256, 0, stream>>>(F, Wp, out);
}

// Round 2
// 115.965 us; speedup vs baseline: 1.4714x; 1.4714x over previous
//
#include <hip/hip_runtime.h>
#include <hip/hip_bf16.h>

// Problem constants
#define B_      4
#define C_IN    64
#define H_      64
#define W_      64
#define OUT_CH  128
#define HP_     66          // padded height (halo = features(0))
#define CF      576         // K per tap: 9 features * 64 channels, cf = j*64 + c
#define WP_BYTES  (9 * OUT_CH * CF * 2)          // 1,327,104
#define F_BYTES   (B_ * HP_ * HP_ * CF * 2)      // 20,072,448
#define P_OFFSET  (WP_BYTES + F_BYTES)           // 21,399,552 (16B aligned)
// partials: 4 K-groups x (4 b x 128 o x 4096 pix) fp16 = 16,777,216 B

typedef __bf16 bf16x8 __attribute__((ext_vector_type(8)));
typedef float  f32x4  __attribute__((ext_vector_type(4)));
typedef _Float16 half8 __attribute__((ext_vector_type(8)));

// silu + cubic B-spline bases (Cox-de Boor), identical semantics to round 1 (passed).
__device__ __forceinline__ void compute_features(float x, float f[9]) {
    f[0] = x / (1.0f + __expf(-x));
    float g[12];
#pragma unroll
    for (int i = 0; i < 12; ++i) g[i] = (float)(i - 3) * 0.4f - 1.0f;
    float bb[11];
#pragma unroll
    for (int i = 0; i < 11; ++i) bb[i] = (x >= g[i] && x < g[i + 1]) ? 1.0f : 0.0f;
#pragma unroll
    for (int i = 0; i < 10; ++i)
        bb[i] = (x - g[i]) * (1.0f / (g[i + 1] - g[i])) * bb[i]
              + (g[i + 2] - x) * (1.0f / (g[i + 2] - g[i + 1])) * bb[i + 1];
#pragma unroll
    for (int i = 0; i < 9; ++i)
        bb[i] = (x - g[i]) * (1.0f / (g[i + 2] - g[i])) * bb[i]
              + (g[i + 3] - x) * (1.0f / (g[i + 3] - g[i + 1])) * bb[i + 1];
#pragma unroll
    for (int i = 0; i < 8; ++i)
        bb[i] = (x - g[i]) * (1.0f / (g[i + 3] - g[i])) * bb[i]
              + (g[i + 4] - x) * (1.0f / (g[i + 4] - g[i + 1])) * bb[i + 1];
#pragma unroll
    for (int i = 0; i < 8; ++i) f[1 + i] = bb[i];
}

// Kernel 1: pack merged weights -> bf16, Wp[(tap*128 + o)*576 + j*64 + c].
// v2: thread <-> sw element (coalesced READS); writes scatter (stores don't stall).
__global__ __launch_bounds__(256) void pack_kernel(
        const float* __restrict__ bw, const float* __restrict__ sw,
        const float* __restrict__ sc, __hip_bfloat16* __restrict__ Wp) {
    int idx = blockIdx.x * 256 + threadIdx.x;          // 0 .. 663551
    if (idx < 589824) {                                 // spline part: idx = o*4608 + d*8 + j
        int o = idx / 4608;
        int r = idx - o * 4608;
        int d = r >> 3;
        int j = r & 7;
        int tap = d % 9;
        int c   = d / 9;
        float v = sw[idx] * sc[o * 576 + d];
        Wp[(tap * OUT_CH + o) * CF + (j + 1) * 64 + c] = __float2bfloat16(v);
    } else {                                            // base part: k = o*576 + d
        int k = idx - 589824;
        int o = k / 576;
        int d = k - o * 576;
        int tap = d % 9;
        int c   = d / 9;
        Wp[(tap * OUT_CH + o) * CF + c] = __float2bfloat16(bw[k]);
    }
}

// Kernel 2: per-pixel features with halo. F[((b*66+hp)*66+wp)*576 + j*64 + c]
// v2: stage x row through LDS so global reads are lane=w coalesced.
__global__ __launch_bounds__(256) void feat_kernel(
        const float* __restrict__ x, __hip_bfloat16* __restrict__ F) {
    __shared__ float xs[64][65];
    int b  = blockIdx.x / HP_;
    int hp = blockIdx.x % HP_;
    int h  = hp - 1;
    int tid = threadIdx.x;

    float f0[9];
    compute_features(0.0f, f0);

    bool interior_row = (h >= 0) && (h < H_);
    if (interior_row) {
        int wl  = tid & 63;
        int c16 = tid >> 6;           // 0..3
#pragma unroll
        for (int i = 0; i < 16; ++i) {
            int c = c16 * 16 + i;
            xs[c][wl] = x[((b * C_IN + c) * H_ + h) * W_ + wl];
        }
    }
    __syncthreads();

    int c  = tid & 63;
    int wg = tid >> 6;                // 0..3
    __hip_bfloat16* Frow = F + (size_t)((b * HP_ + hp) * HP_) * CF;

    if (!interior_row) {
        for (int wp = wg; wp < HP_; wp += 4) {
            __hip_bfloat16* dst = Frow + (size_t)wp * CF + c;
#pragma unroll
            for (int j = 0; j < 9; ++j) dst[j * 64] = __float2bfloat16(f0[j]);
        }
        return;
    }
    // wp halos
    if (wg == 0) {
        __hip_bfloat16* dst = Frow + c;                      // wp = 0
#pragma unroll
        for (int j = 0; j < 9; ++j) dst[j * 64] = __float2bfloat16(f0[j]);
    }
    if (wg == 3) {
        __hip_bfloat16* dst = Frow + (size_t)65 * CF + c;    // wp = 65
#pragma unroll
        for (int j = 0; j < 9; ++j) dst[j * 64] = __float2bfloat16(f0[j]);
    }
    // interior
    for (int w2 = wg; w2 < 64; w2 += 4) {
        float xv = xs[c][w2];          // bank = (c + w2) % 32 -> 2-way, free
        float f[9];
        compute_features(xv, f);
        __hip_bfloat16* dst = Frow + (size_t)(w2 + 1) * CF + c;
#pragma unroll
        for (int j = 0; j < 9; ++j) dst[j * 64] = __float2bfloat16(f[j]);
    }
}

// Kernel 3: implicit-GEMM conv, 4-way K-split.
// Grid = 512: blk = g*128 + t; g = K-group (chunks of BK=64 over taps), t = pixel tile
// (128 pixels = 2 image rows) x all 128 out_ch. 4 waves in 2x2, wave = 64 o x 64 pix
// of 16x16x32 bf16 MFMA. Staging via global_load_lds dwordx4 into XOR-swizzled LDS
// (granule (row,c8) lives at slot row*8 + (c8 ^ (row&7))), double-buffered, one
// barrier per chunk. Partials stored fp16.
__global__ __launch_bounds__(256, 2) void gemm_kernel(
        const __hip_bfloat16* __restrict__ Fb, const __hip_bfloat16* __restrict__ Wpb,
        _Float16* __restrict__ P) {
    __shared__ __align__(16) ushort As[2][8192];   // pixels:  [pix 0..127][cf 0..63] swizzled
    __shared__ __align__(16) ushort Bs[2][8192];   // weights: [o 0..127][cf 0..63] swizzled

    const ushort* F  = (const ushort*)Fb;
    const ushort* Wp = (const ushort*)Wpb;

    int tid  = threadIdx.x;
    int lane = tid & 63;
    int w    = tid >> 6;
    int l15  = lane & 15;
    int lq   = lane >> 4;
    int wm = w & 1;                  // out_ch half
    int wn = w >> 1;                 // pixel half
    int srow = lane >> 3;            // 0..7 staging sub-row
    int sl7  = lane & 7;
    int c8s  = sl7 ^ srow;           // staged c8 for this lane (swizzle-inverse)

    int blk = blockIdx.x;
    int g   = blk >> 7;              // K-group 0..3
    int t   = blk & 127;
    int b   = t >> 5;
    int ho0 = (t & 31) << 1;
    int c0 = (g == 0) ? 0 : (21 + 20 * (g - 1));   // {0,21,41,61}
    int c1 = c0 + ((g == 0) ? 21 : 20);            // 81 chunks total (tap*9 + kc)

    f32x4 acc[4][4];
#pragma unroll
    for (int i = 0; i < 4; ++i)
#pragma unroll
        for (int j = 0; j < 4; ++j) acc[i][j] = (f32x4){0.f, 0.f, 0.f, 0.f};

    auto prefetch = [&](int ch, int buf) {
        int tap = ch / 9;
        int kc  = ch - tap * 9;
        int kh  = tap / 3;
        int kw  = tap - kh * 3;
#pragma unroll
        for (int r = 0; r < 4; ++r) {
            int row = (r * 4 + w) * 8 + srow;       // 0..127 (pix or o)
            // A: features, tap-shifted pixel
            int hp = ho0 + (row >> 6) + kh;
            int wp = (row & 63) + kw;
            const ushort* srcA = F + (size_t)((b * HP_ + hp) * HP_ + wp) * CF
                                   + kc * 64 + c8s * 8;
            __builtin_amdgcn_global_load_lds(
                (const __attribute__((address_space(1))) unsigned int*)srcA,
                (__attribute__((address_space(3))) unsigned int*)&As[buf][(r * 4 + w) * 512],
                16, 0, 0);
            // B: weights
            const ushort* srcB = Wp + (size_t)(tap * OUT_CH + row) * CF
                                    + kc * 64 + c8s * 8;
            __builtin_amdgcn_global_load_lds(
                (const __attribute__((address_space(1))) unsigned int*)srcB,
                (__attribute__((address_space(3))) unsigned int*)&Bs[buf][(r * 4 + w) * 512],
                16, 0, 0);
        }
    };

    int buf = 0;
    prefetch(c0, 0);
    for (int ch = c0; ch < c1; ++ch) {
        __syncthreads();                       // drains vmcnt -> buf ready; prev readers done
        if (ch + 1 < c1) prefetch(ch + 1, buf ^ 1);
#pragma unroll
        for (int ks = 0; ks < 2; ++ks) {
            bf16x8 af[4], bq[4];
#pragma unroll
            for (int mt = 0; mt < 4; ++mt) {
                int o  = wm * 64 + mt * 16 + l15;
                int sl = o * 8 + ((ks * 4 + lq) ^ (o & 7));
                af[mt] = *(const bf16x8*)&Bs[buf][sl * 8];
            }
#pragma unroll
            for (int nt = 0; nt < 4; ++nt) {
                int p  = wn * 64 + nt * 16 + l15;
                int sl = p * 8 + ((ks * 4 + lq) ^ (p & 7));
                bq[nt] = *(const bf16x8*)&As[buf][sl * 8];
            }
#pragma unroll
            for (int mt = 0; mt < 4; ++mt)
#pragma unroll
                for (int nt = 0; nt < 4; ++nt)
                    acc[mt][nt] = __builtin_amdgcn_mfma_f32_16x16x32_bf16(
                        af[mt], bq[nt], acc[mt][nt], 0, 0, 0);
        }
        buf ^= 1;
    }

    // epilogue: fp16 partials. P[((g*4+b)*128 + o)*4096 + ho0*64 + pix]
    _Float16* Pg = P + ((size_t)(g * 4 + b) * OUT_CH) * 4096 + ho0 * 64;
#pragma unroll
    for (int mt = 0; mt < 4; ++mt) {
        int o = wm * 64 + mt * 16 + lq * 4;
#pragma unroll
        for (int nt = 0; nt < 4; ++nt) {
            int pix = wn * 64 + nt * 16 + l15;
            _Float16* dst = Pg + (size_t)o * 4096 + pix;
#pragma unroll
            for (int r = 0; r < 4; ++r)
                dst[(size_t)r * 4096] = (_Float16)acc[mt][nt][r];
        }
    }
}

// Kernel 4: reduce 4 fp16 partials -> fp32 out. Fully coalesced half8/float4.
__global__ __launch_bounds__(256) void reduce_kernel(
        const half8* __restrict__ P, float4* __restrict__ out) {
    const int GS = 262144;                    // half8 per K-group (4*128*4096/8)
    int i = blockIdx.x * 256 + threadIdx.x;   // 0..262143
    half8 a = P[i], bb = P[GS + i], c = P[2 * GS + i], d = P[3 * GS + i];
    float4 o0, o1;
#pragma unroll
    for (int j = 0; j < 4; ++j)
        ((float*)&o0)[j] = (float)a[j] + (float)bb[j] + (float)c[j] + (float)d[j];
#pragma unroll
    for (int j = 0; j < 4; ++j)
        ((float*)&o1)[j] = (float)a[4 + j] + (float)bb[4 + j] + (float)c[4 + j] + (float)d[4 + j];
    out[i * 2]     = o0;
    out[i * 2 + 1] = o1;
}

extern "C" void kernel_launch(void* const* d_in, const int* in_sizes, int n_in,
                              void* d_out, int out_size, void* d_ws, size_t ws_size,
                              hipStream_t stream) {
    const float* x  = (const float*)d_in[0];   // (4,64,64,64)
    const float* bw = (const float*)d_in[1];   // (128,576)
    const float* sw = (const float*)d_in[2];   // (128,576,8)
    const float* sc = (const float*)d_in[3];   // (128,576)
    float* out = (float*)d_out;                // (4,128,64,64) fp32

    __hip_bfloat16* Wp = (__hip_bfloat16*)d_ws;
    __hip_bfloat16* F  = (__hip_bfloat16*)((char*)d_ws + WP_BYTES);
    _Float16*       P  = (_Float16*)((char*)d_ws + P_OFFSET);

    pack_kernel<<<2592, 256, 0, stream>>>(bw, sw, sc, Wp);
    feat_kernel<<<B_ * HP_, 256, 0, stream>>>(x, F);
    gemm_kernel<<<512, 256, 0, stream>>>(F, Wp, P);
    reduce_kernel<<<1024, 256, 0, stream>>>((const half8*)P, (float4*)out);
}